// Round 6
// baseline (136.537 us; speedup 1.0000x reference)
//
#include <hip/hip_runtime.h>
#include <hip/hip_bf16.h>
#include <math.h>

#define EPSV 1e-5f
#define HD   128
#define AROW 40   // bf16 row stride: 80B. b128 ops at this stride are conflict-free
                  // (dword-quartet index 5*tid+w is bijective mod 8 per 8-lane phase).

typedef __attribute__((ext_vector_type(8))) short bf16x8;   // 8 bf16 = 4 VGPRs
typedef __attribute__((ext_vector_type(4))) float f32x4;

// d_ws layout (bytes):
//   [0,      8192)   Wt1: bf16[128][32]  whi duplicated in k=0..15 / 16..31 halves
//   [8192,  16384)   Wt2: bf16[128][32]  wlo duplicated
//   [16384, 81920)   W1t: f32[128][128]  W1 transposed (row j = column j of W1)
//   [81920, 147456)  W2t: f32[128][128]  W2 transposed
__global__ __launch_bounds__(256) void prep_weights(
    const float* __restrict__ W0, const float* __restrict__ W1,
    const float* __restrict__ W2, __hip_bfloat16* __restrict__ wt1,
    __hip_bfloat16* __restrict__ wt2, float* __restrict__ w1t,
    float* __restrict__ w2t)
{
    if (blockIdx.x == 0) {
        // MFMA B-operand tables for the 9 particle-varying W0 rows.
        const int RV[9] = {0, 1, 2, 3, 14, 15, 16, 17, 18};
        for (int i = threadIdx.x; i < 128 * 32; i += 256) {
            const int n  = i >> 5;
            const int kk = i & 15;        // k mod 16 (hi/lo halves duplicated)
            float val = 0.0f;
            if (n < 127 && kk < 9) val = W0[RV[kk] * 127 + n];
            const __hip_bfloat16 hi = __float2bfloat16(val);
            const __hip_bfloat16 lo = __float2bfloat16(val - __bfloat162float(hi));
            wt1[i] = hi;
            wt2[i] = lo;
        }
    } else {
        // Transpose W1 and W2 (each 128x128 f32).
        const int base = (blockIdx.x - 1) * 2048;
        for (int t = threadIdx.x; t < 2048; t += 256) {
            const int idx = base + t;            // 0..32767
            const float* src = (idx < 16384) ? W1 : W2;
            float*       dst = (idx < 16384) ? w1t : w2t;
            const int e = idx & 16383;
            const int j = e >> 7, k = e & 127;
            dst[j * 128 + k] = src[k * 128 + j];
        }
    }
}

// One block per (b,t). blockDim = 256 = ND. 4 waves. 5 barriers.
// Layer 0: 10 per-(b,t)-constant features -> exact fp32 c[n]; 9 varying
// features -> compensated bf16 MFMA (A: hi k0..8 | lo k16..24; B1=whi dup,
// B2=wlo dup => 2 MFMAs give exact (ahi+alo)*(whi+wlo)).
__global__ __launch_bounds__(256, 4) void net_fused(
    const float* __restrict__ x0g, const float* __restrict__ xg,
    const int*   __restrict__ Ng,  const float* __restrict__ basisg,
    const float* __restrict__ vg,  const float* __restrict__ Pg,
    const float* __restrict__ W0,  const float* __restrict__ b0,
    const float* __restrict__ b1,  const float* __restrict__ b2,
    const __hip_bfloat16* __restrict__ wt1g,
    const __hip_bfloat16* __restrict__ wt2g,
    const float* __restrict__ w1t, const float* __restrict__ w2t,
    float* __restrict__ out, int Tn, int NDn)
{
    __shared__ __align__(16) __hip_bfloat16 SA[256 * AROW];  // varying feats hi|lo
    __shared__ float cvec[HD];        // exact constant-feature contribution
    __shared__ float part[4][HD];     // per-wave pooled partials
    __shared__ __align__(16) float hvec[HD];
    __shared__ __align__(16) float h1vec[HD];
    __shared__ float vred[4][3];      // v-mean wave partials

    const int bt   = blockIdx.x;
    const int b    = bt / Tn;
    const int tid  = threadIdx.x;
    const int lane = tid & 63;
    const int wave = tid >> 6;

    // ---- per-particle global loads (particle i = tid) ----
    const long pbase = ((long)bt * NDn + tid) * 3;
    const float xi0 = xg[pbase+0], xi1 = xg[pbase+1], xi2 = xg[pbase+2];
    const float vi0 = vg[pbase+0], vi1 = vg[pbase+1], vi2 = vg[pbase+2];

    // ---- v0 = mean_n v : wave shuffle reduce + LDS combine ----
    float s0 = vi0, s1 = vi1, s2 = vi2;
    #pragma unroll
    for (int off = 32; off > 0; off >>= 1) {
        s0 += __shfl_down(s0, off);
        s1 += __shfl_down(s1, off);
        s2 += __shfl_down(s2, off);
    }
    if (lane == 0) { vred[wave][0] = s0; vred[wave][1] = s1; vred[wave][2] = s2; }
    __syncthreads();                                             // B1

    const float inv_nd = 1.0f / (float)NDn;
    const float v00 = (vred[0][0]+vred[1][0]+vred[2][0]+vred[3][0]) * inv_nd;
    const float v01 = (vred[0][1]+vred[1][1]+vred[2][1]+vred[3][1]) * inv_nd;
    const float v02 = (vred[0][2]+vred[1][2]+vred[2][2]+vred[3][2]) * inv_nd;

    // ---- per-(b,t) scalars ----
    const float p0 = x0g[bt*3+0], p1 = x0g[bt*3+1], p2 = x0g[bt*3+2];
    float bas[3][3];
    #pragma unroll
    for (int k = 0; k < 3; ++k)
        #pragma unroll
        for (int c = 0; c < 3; ++c)
            bas[k][c] = basisg[(b*3 + k)*3 + c];

    const float x0n  = sqrtf(p0*p0 + p1*p1 + p2*p2) + EPSV;
    const float ix0n = 1.0f / x0n;
    const float x0u0 = p0*ix0n, x0u1 = p1*ix0n, x0u2 = p2*ix0n;

    const float v0n  = sqrtf(v00*v00 + v01*v01 + v02*v02) + EPSV;
    const float iv0n = 1.0f / v0n;
    const float v0u0 = v00*iv0n, v0u1 = v01*iv0n, v0u2 = v02*iv0n;

    const float logN = log1pf((float)Ng[bt]);

    // ---- exact fp32 constant-feature contribution c[n] (W0 rows 4..13) ----
    if (tid < 128) {
        float c = 0.0f;
        if (tid < 127) {
            float fc[10];
            fc[0] = logN;
            fc[1] = x0n;
            fc[2] = x0u0*bas[0][0] + x0u1*bas[0][1] + x0u2*bas[0][2];
            fc[3] = x0u0*bas[1][0] + x0u1*bas[1][1] + x0u2*bas[1][2];
            fc[4] = x0u0*bas[2][0] + x0u1*bas[2][1] + x0u2*bas[2][2];
            fc[5] = v0n;
            fc[6] = v0u0*bas[0][0] + v0u1*bas[0][1] + v0u2*bas[0][2];
            fc[7] = v0u0*bas[1][0] + v0u1*bas[1][1] + v0u2*bas[1][2];
            fc[8] = v0u0*bas[2][0] + v0u1*bas[2][1] + v0u2*bas[2][2];
            fc[9] = x0u0*v0u0 + x0u1*v0u1 + x0u2*v0u2;
            c = b0[tid];
            #pragma unroll
            for (int i = 0; i < 10; ++i)
                c = fmaf(fc[i], W0[(4 + i) * 127 + tid], c);
        }
        cvec[tid] = c;
    }

    // ---- per-particle varying features -> LDS via 4x ds_write_b128 ----
    {
        const float xn  = sqrtf(xi0*xi0 + xi1*xi1 + xi2*xi2) + EPSV;
        const float ixn = 1.0f / xn;
        const float xu0 = xi0*ixn, xu1 = xi1*ixn, xu2 = xi2*ixn;

        const float c0 = vi0 - v00, c1 = vi1 - v01, c2 = vi2 - v02;
        const float vn  = sqrtf(c0*c0 + c1*c1 + c2*c2) + EPSV;
        const float ivn = 1.0f / vn;
        const float vu0 = c0*ivn, vu1 = c1*ivn, vu2 = c2*ivn;

        float f[9];
        f[0] = xn;                                            // W0 row 0
        f[1] = xu0*bas[0][0] + xu1*bas[0][1] + xu2*bas[0][2]; // row 1
        f[2] = xu0*bas[1][0] + xu1*bas[1][1] + xu2*bas[1][2]; // row 2
        f[3] = xu0*bas[2][0] + xu1*bas[2][1] + xu2*bas[2][2]; // row 3
        f[4] = vn;                                            // row 14
        f[5] = vu0*bas[0][0] + vu1*bas[0][1] + vu2*bas[0][2]; // row 15
        f[6] = vu0*bas[1][0] + vu1*bas[1][1] + vu2*bas[1][2]; // row 16
        f[7] = vu0*bas[2][0] + vu1*bas[2][1] + vu2*bas[2][2]; // row 17
        f[8] = xu0*vu0 + xu1*vu1 + xu2*vu2;                   // row 18

        __hip_bfloat16 row[32];
        #pragma unroll
        for (int kk = 0; kk < 32; ++kk) row[kk] = __float2bfloat16(0.0f);
        #pragma unroll
        for (int kk = 0; kk < 9; ++kk) {
            const __hip_bfloat16 hi = __float2bfloat16(f[kk]);
            row[kk]      = hi;
            row[16 + kk] = __float2bfloat16(f[kk] - __bfloat162float(hi));
        }
        bf16x8* dst = reinterpret_cast<bf16x8*>(&SA[tid * AROW]);
        const bf16x8* src = reinterpret_cast<const bf16x8*>(row);
        dst[0] = src[0];
        dst[1] = src[1];
        dst[2] = src[2];
        dst[3] = src[3];
    }
    __syncthreads();                                             // B2

    // ---- layer 0 via MFMA: wave w owns particles [w*64, w*64+64) x 128 cols ----
    {
        const int quad = lane >> 4;
        const int lm   = lane & 15;

        bf16x8 afr[4];
        #pragma unroll
        for (int mt = 0; mt < 4; ++mt)
            afr[mt] = *reinterpret_cast<const bf16x8*>(
                &SA[(wave*64 + mt*16 + lm) * AROW + quad*8]);

        const f32x4 zero = {0.f, 0.f, 0.f, 0.f};
        #pragma unroll
        for (int nt = 0; nt < 8; ++nt) {
            const int woff = ((nt*16 + lm) * 32 + quad*8);
            const bf16x8 bh = *reinterpret_cast<const bf16x8*>(&wt1g[woff]);
            const bf16x8 bl = *reinterpret_cast<const bf16x8*>(&wt2g[woff]);
            const float  cl = cvec[nt*16 + lm];
            float p = 0.0f;
            #pragma unroll
            for (int mt = 0; mt < 4; ++mt) {
                f32x4 acc = __builtin_amdgcn_mfma_f32_16x16x32_bf16(afr[mt], bh, zero, 0, 0, 0);
                acc = __builtin_amdgcn_mfma_f32_16x16x32_bf16(afr[mt], bl, acc, 0, 0, 0);
                #pragma unroll
                for (int r = 0; r < 4; ++r) {
                    const float d = acc[r] + cl;
                    p += fmaxf(d, 0.01f*d);          // leaky_relu
                }
            }
            p += __shfl_xor(p, 16);
            p += __shfl_xor(p, 32);
            if (lane < 16) part[wave][nt*16 + lane] = p;
        }
    }
    __syncthreads();                                             // B3

    if (tid < HD) {
        const float p = part[0][tid] + part[1][tid] + part[2][tid] + part[3][tid];
        hvec[tid] = (tid < 127) ? p * inv_nd : logN;
    }
    __syncthreads();                                             // B4

    // ---- layer 1: thread j computes full-K GEMV with transposed weights ----
    if (tid < HD) {
        float a = b1[tid];
        const float4* wr = reinterpret_cast<const float4*>(&w1t[tid * 128]);
        const float4* hv = reinterpret_cast<const float4*>(hvec);
        #pragma unroll 8
        for (int kk = 0; kk < 32; ++kk) {
            const float4 h4 = hv[kk];
            const float4 w4 = wr[kk];
            a = fmaf(h4.x, w4.x, a);
            a = fmaf(h4.y, w4.y, a);
            a = fmaf(h4.z, w4.z, a);
            a = fmaf(h4.w, w4.w, a);
        }
        h1vec[tid] = fmaxf(a, 0.01f*a);
    }
    __syncthreads();                                             // B5

    // ---- layer 2 + output scale ----
    if (tid < HD) {
        float a = b2[tid];
        const float4* wr = reinterpret_cast<const float4*>(&w2t[tid * 128]);
        const float4* hv = reinterpret_cast<const float4*>(h1vec);
        #pragma unroll 8
        for (int kk = 0; kk < 32; ++kk) {
            const float4 h4 = hv[kk];
            const float4 w4 = wr[kk];
            a = fmaf(h4.x, w4.x, a);
            a = fmaf(h4.y, w4.y, a);
            a = fmaf(h4.z, w4.z, a);
            a = fmaf(h4.w, w4.w, a);
        }
        out[(long)bt * HD + tid] = a / Pg[b];
    }
}

extern "C" void kernel_launch(void* const* d_in, const int* in_sizes, int n_in,
                              void* d_out, int out_size, void* d_ws, size_t ws_size,
                              hipStream_t stream) {
    const float* x0    = (const float*)d_in[0];
    const float* x     = (const float*)d_in[1];
    const int*   N     = (const int*)  d_in[2];
    const float* basis = (const float*)d_in[3];
    const float* v     = (const float*)d_in[4];
    const float* P200c = (const float*)d_in[5];
    const float* W0    = (const float*)d_in[6];
    const float* b0    = (const float*)d_in[7];
    const float* W1    = (const float*)d_in[8];
    const float* b1    = (const float*)d_in[9];
    const float* W2    = (const float*)d_in[10];
    const float* b2    = (const float*)d_in[11];
    float* out = (float*)d_out;

    const int B  = in_sizes[5];                 // P200c is [B]
    const int T  = in_sizes[2] / B;             // N is [B,T]
    const int ND = in_sizes[1] / (in_sizes[2] * 3);  // x is [B,T,ND,3]

    char* ws = (char*)d_ws;
    __hip_bfloat16* wt1 = (__hip_bfloat16*)(ws);
    __hip_bfloat16* wt2 = (__hip_bfloat16*)(ws + 8192);
    float*          w1t = (float*)(ws + 16384);
    float*          w2t = (float*)(ws + 81920);

    hipLaunchKernelGGL(prep_weights, dim3(17), dim3(256), 0, stream,
                       W0, W1, W2, wt1, wt2, w1t, w2t);

    hipLaunchKernelGGL(net_fused, dim3(B * T), dim3(256), 0, stream,
                       x0, x, N, basis, v, P200c, W0, b0, b1, b2,
                       wt1, wt2, w1t, w2t, out, T, ND);
}